// Round 3
// baseline (1205.608 us; speedup 1.0000x reference)
//
#include <hip/hip_runtime.h>

// NonLinearSAGE: only nodes i % 3 == 0 reach the output -> aggregate only
// edges with dst % 3 == 0 into compact agg[dst/3] (1M floats).
//
// R3 change: device-scope fp32 atomics were the limiter (500 MB of 32B RMW
// packets to the fabric, ~20 G atomics/s). Privatize agg into 8 per-XCD
// copies selected by HW_REG_XCC_ID and use workgroup-scope atomics, which
// execute in the XCD-local L2 (all CUs of an XCD share that L2, so same-XCD
// blocks serialize correctly; cross-XCD races impossible since copies are
// disjoint). Finalize sums the 8 copies.

static constexpr int kEdges = 48000000;
static constexpr int kOut   = 1000000;   // kNodes / 3

typedef int v4i __attribute__((ext_vector_type(4)));

__device__ __forceinline__ unsigned xcc_id() {
    // s_getreg_b32 hwreg(HW_REG_XCC_ID=20, offset=0, size=4)  [learn_hip m09]
    return (unsigned)__builtin_amdgcn_s_getreg((3 << 11) | 20) & 7u;
}

__global__ __launch_bounds__(256) void edge_scatter_priv(
    const int* __restrict__ ei,
    const float* __restrict__ x,
    float* __restrict__ copies)   // 8 * kOut floats
{
    const int tid = blockIdx.x * blockDim.x + threadIdx.x;
    const int e = tid * 4;                 // kEdges divisible by 4
    if (e >= kEdges) return;

    float* myagg = copies + (size_t)xcc_id() * kOut;

    // Non-temporal: don't let the 384 MB edge stream evict x / agg copy from L2.
    const v4i s4 = __builtin_nontemporal_load(reinterpret_cast<const v4i*>(ei + e));
    const v4i d4 = __builtin_nontemporal_load(reinterpret_cast<const v4i*>(ei + kEdges + e));

    const int ss[4] = {s4.x, s4.y, s4.z, s4.w};
    const int dd[4] = {d4.x, d4.y, d4.z, d4.w};

#pragma unroll
    for (int k = 0; k < 4; ++k) {
        const unsigned d = (unsigned)dd[k];
        const unsigned q = d / 3u;         // magic-multiply
        if (q * 3u == d) {                 // dst % 3 == 0
            // Workgroup scope -> executes at XCD-local L2 (no fabric RMW packet).
            __hip_atomic_fetch_add(myagg + q, x[ss[k]],
                                   __ATOMIC_RELAXED, __HIP_MEMORY_SCOPE_WORKGROUP);
        }
    }
}

// Fallback (ws too small): single copy, device-scope atomics (R2 behavior).
__global__ __launch_bounds__(256) void edge_scatter_dev(
    const int* __restrict__ ei,
    const float* __restrict__ x,
    float* __restrict__ agg)
{
    const int tid = blockIdx.x * blockDim.x + threadIdx.x;
    const int e = tid * 4;
    if (e >= kEdges) return;

    const v4i s4 = __builtin_nontemporal_load(reinterpret_cast<const v4i*>(ei + e));
    const v4i d4 = __builtin_nontemporal_load(reinterpret_cast<const v4i*>(ei + kEdges + e));

    const int ss[4] = {s4.x, s4.y, s4.z, s4.w};
    const int dd[4] = {d4.x, d4.y, d4.z, d4.w};

#pragma unroll
    for (int k = 0; k < 4; ++k) {
        const unsigned d = (unsigned)dd[k];
        const unsigned q = d / 3u;
        if (q * 3u == d) {
            atomicAdd(agg + q, x[ss[k]]);
        }
    }
}

__global__ __launch_bounds__(256) void finalize(
    const float* __restrict__ copies, int ncopies,
    const float* __restrict__ x,
    const float* __restrict__ Wl,
    const float* __restrict__ Wr,
    const float* __restrict__ W1,
    const float* __restrict__ b1,
    const float* __restrict__ W2,
    const float* __restrict__ b2,
    float* __restrict__ out)
{
    const int j = blockIdx.x * blockDim.x + threadIdx.x;
    if (j >= kOut) return;

    float a = 0.0f;
    for (int c = 0; c < ncopies; ++c)
        a += copies[(size_t)c * kOut + j];

    const float h = a * Wl[0] + x[3 * j] * Wr[0];
    const float t0 = fmaxf(h * W1[0] + b1[0], 0.0f);
    const float t1 = fmaxf(h * W1[1] + b1[1], 0.0f);
    out[j] = t0 * W2[0] + t1 * W2[1] + b2[0];
}

extern "C" void kernel_launch(void* const* d_in, const int* in_sizes, int n_in,
                              void* d_out, int out_size, void* d_ws, size_t ws_size,
                              hipStream_t stream)
{
    const float* x  = (const float*)d_in[0];
    const int*   ei = (const int*)d_in[1];
    const float* Wl = (const float*)d_in[2];
    const float* Wr = (const float*)d_in[3];
    const float* W1 = (const float*)d_in[4];
    const float* b1 = (const float*)d_in[5];
    const float* W2 = (const float*)d_in[6];
    const float* b2 = (const float*)d_in[7];
    float* out = (float*)d_out;

    float* copies = (float*)d_ws;
    const size_t needPriv = 8ull * kOut * sizeof(float);   // 32 MB

    const int nScatterBlocks = (kEdges / 4) / 256;         // 46875
    const int nFinBlocks = (kOut + 255) / 256;

    if (ws_size >= needPriv) {
        hipMemsetAsync(copies, 0, needPriv, stream);
        edge_scatter_priv<<<nScatterBlocks, 256, 0, stream>>>(ei, x, copies);
        finalize<<<nFinBlocks, 256, 0, stream>>>(copies, 8, x, Wl, Wr, W1, b1, W2, b2, out);
    } else {
        hipMemsetAsync(copies, 0, kOut * sizeof(float), stream);
        edge_scatter_dev<<<nScatterBlocks, 256, 0, stream>>>(ei, x, copies);
        finalize<<<nFinBlocks, 256, 0, stream>>>(copies, 1, x, Wl, Wr, W1, b1, W2, b2, out);
    }
}